// Round 1
// baseline (255.214 us; speedup 1.0000x reference)
//
#include <hip/hip_runtime.h>
#include <math.h>

// Problem constants (match reference)
#define DIM   256   // INNER_DIM (D)
#define NST   256   // STATE_DIM (N)
#define LSEQ  512
#define BAT   2
#define DTSZ  64
#define PCOLS 576   // DTSZ + 2*DIM
#define NROWS (BAT * LSEQ)  // 1024

// ---------------- Kernel 1: proj = x@W_in, dt = softplus(dt_raw@W_dt + b_dt), dtx = dt*x
// 256 blocks x 256 threads; each block handles ROWS=4 rows (b,l pairs).
// Thread j owns output columns {j, 256+j, 512+j (j<64)} of proj.
constexpr int ROWS = 4;

__global__ __launch_bounds__(256) void proj_kernel(
    const float* __restrict__ x,      // [NROWS, DIM]
    const float* __restrict__ W_in,   // [DIM, PCOLS]
    const float* __restrict__ W_dt,   // [DTSZ, DIM]
    const float* __restrict__ b_dt,   // [DIM]
    float* __restrict__ bet,          // [NROWS, NST]
    float* __restrict__ gam,          // [NROWS, NST]
    float* __restrict__ dtp,          // [NROWS, DIM]
    float* __restrict__ dtxp)         // [NROWS, DIM]
{
    __shared__ float xs[ROWS][DIM];
    __shared__ float draw[ROWS][DTSZ];
    const int j = threadIdx.x;
    const int row0 = blockIdx.x * ROWS;

    #pragma unroll
    for (int r = 0; r < ROWS; ++r) xs[r][j] = x[(row0 + r) * DIM + j];
    __syncthreads();

    float acc0[ROWS] = {0.f, 0.f, 0.f, 0.f};
    float acc1[ROWS] = {0.f, 0.f, 0.f, 0.f};
    float acc2[ROWS] = {0.f, 0.f, 0.f, 0.f};
    const bool has2 = (j < 64);

    for (int k = 0; k < DIM; ++k) {
        float w0 = W_in[k * PCOLS + j];
        float w1 = W_in[k * PCOLS + 256 + j];
        float w2 = has2 ? W_in[k * PCOLS + 512 + j] : 0.f;
        #pragma unroll
        for (int r = 0; r < ROWS; ++r) {
            float xv = xs[r][k];          // LDS broadcast (same addr across lanes)
            acc0[r] = fmaf(xv, w0, acc0[r]);
            acc1[r] = fmaf(xv, w1, acc1[r]);
            acc2[r] = fmaf(xv, w2, acc2[r]);
        }
    }

    // Scatter proj columns: col c: c<64 -> dt_raw[c]; 64<=c<320 -> beta[c-64]; else gamma[c-320]
    #pragma unroll
    for (int r = 0; r < ROWS; ++r) {
        const int row = row0 + r;
        if (j < 64) {
            draw[r][j] = acc0[r];                        // dt_raw
            bet[row * NST + 192 + j] = acc1[r];          // col 256+j in [256,320)
            gam[row * NST + 192 + j] = acc2[r];          // col 512+j in [512,576)
        } else {
            bet[row * NST + (j - 64)] = acc0[r];         // col j in [64,320)
            gam[row * NST + (j - 64)] = acc1[r];         // col 256+j in [320,512)
        }
    }
    __syncthreads();

    // Phase 2: dt = softplus(dt_raw @ W_dt + b_dt); dtx = dt * x
    float bd = b_dt[j];
    float accd[ROWS];
    #pragma unroll
    for (int r = 0; r < ROWS; ++r) accd[r] = bd;
    for (int k = 0; k < DTSZ; ++k) {
        float w = W_dt[k * DIM + j];
        #pragma unroll
        for (int r = 0; r < ROWS; ++r) accd[r] = fmaf(draw[r][k], w, accd[r]);
    }
    #pragma unroll
    for (int r = 0; r < ROWS; ++r) {
        const int row = row0 + r;
        float v = accd[r];
        float sp = (v > 20.f) ? v : log1pf(__expf(v));   // softplus
        dtp[row * DIM + j] = sp;
        dtxp[row * DIM + j] = sp * xs[r][j];
    }
}

// ---------------- Kernel 2: the scan
// 512 blocks (one per (b,d)) x 256 threads (thread = state index n).
// State lives in a register. Per-step output contributions go to LDS;
// a batched transpose-reduction every TB=32 steps produces y for 32 steps.
constexpr int TB = 32;

__global__ __launch_bounds__(256) void scan_kernel(
    const float* __restrict__ x,          // [NROWS, DIM]
    const float* __restrict__ alpha_log,  // [DIM, NST]
    const float* __restrict__ delta,      // [DIM]
    const float* __restrict__ bet,        // [NROWS, NST]
    const float* __restrict__ gam,        // [NROWS, NST]
    const float* __restrict__ dtp,        // [NROWS, DIM]
    const float* __restrict__ dtxp,       // [NROWS, DIM]
    float* __restrict__ out)              // [NROWS, DIM]
{
    __shared__ float part[TB][NST];
    const int n = threadIdx.x;
    const int b = blockIdx.x >> 8;
    const int d = blockIdx.x & 255;

    const float aln = -__expf(alpha_log[d * NST + n]);  // alpha[d,n], constant over l
    const float deltad = delta[d];
    const int rbase = b * LSEQ;

    float s = 0.f;

    for (int tb = 0; tb < LSEQ / TB; ++tb) {
        const int l0 = tb * TB;
        #pragma unroll
        for (int t = 0; t < TB; ++t) {
            const int r = rbase + l0 + t;
            float dtv  = dtp[r * DIM + d];    // uniform across block -> scalar load
            float dtxv = dtxp[r * DIM + d];   // uniform
            float be = bet[r * NST + n];      // coalesced
            float ga = gam[r * NST + n];      // coalesced
            float a = __expf(dtv * aln);
            s = fmaf(a, s, dtxv * be);
            part[t][n] = s * ga;              // 2-way bank alias only (free)
        }
        __syncthreads();

        // Reduce 32 steps x 256 partials with 256 threads:
        // thread -> (t = n>>3, seg = n&7), each sums 32 values (rotated k -> conflict-free),
        // then combine the 8 segments with shfl_xor within aligned lane groups of 8.
        {
            const int t = n >> 3;
            const int seg = n & 7;
            float sum = 0.f;
            #pragma unroll
            for (int k = 0; k < 32; ++k) {
                int kk = (k + n) & 31;        // rotation: distinct banks across lanes
                sum += part[t][seg * 32 + kk];
            }
            sum += __shfl_xor(sum, 1);
            sum += __shfl_xor(sum, 2);
            sum += __shfl_xor(sum, 4);
            if (seg == 0) {
                const int idx = (rbase + l0 + t) * DIM + d;
                out[idx] = sum + x[idx] * deltad;
            }
        }
        __syncthreads();
    }
}

extern "C" void kernel_launch(void* const* d_in, const int* in_sizes, int n_in,
                              void* d_out, int out_size, void* d_ws, size_t ws_size,
                              hipStream_t stream) {
    const float* x         = (const float*)d_in[0];
    const float* W_in      = (const float*)d_in[1];
    const float* W_dt      = (const float*)d_in[2];
    const float* b_dt      = (const float*)d_in[3];
    const float* alpha_log = (const float*)d_in[4];
    const float* delta     = (const float*)d_in[5];
    float* out = (float*)d_out;

    // Workspace layout: 4 arrays of [1024 x 256] fp32 = 4 MB total
    float* bet  = (float*)d_ws;
    float* gam  = bet  + NROWS * NST;
    float* dtp  = gam  + NROWS * NST;
    float* dtxp = dtp  + NROWS * DIM;

    proj_kernel<<<NROWS / ROWS, 256, 0, stream>>>(x, W_in, W_dt, b_dt, bet, gam, dtp, dtxp);
    scan_kernel<<<BAT * DIM, 256, 0, stream>>>(x, alpha_log, delta, bet, gam, dtp, dtxp, out);
}

// Round 2
// 136.805 us; speedup vs baseline: 1.8655x; 1.8655x over previous
//
#include <hip/hip_runtime.h>
#include <math.h>

// Problem constants (match reference)
#define DIM   256   // INNER_DIM (D)
#define NST   256   // STATE_DIM (N)
#define LSEQ  512
#define BAT   2
#define DTSZ  64
#define PCOLS 576   // DTSZ + 2*DIM
#define NROWS (BAT * LSEQ)  // 1024

// ---------------- Kernel 1: proj = x@W_in, dt = softplus(dt_raw@W_dt + b_dt), dtx = dt*x
// 512 blocks x 256 threads; each block handles ROWS=2 rows (b,l pairs).
// Thread j owns output columns {j, 256+j, 512+j (j<64)} of proj.
constexpr int ROWS = 2;

__global__ __launch_bounds__(256) void proj_kernel(
    const float* __restrict__ x,      // [NROWS, DIM]
    const float* __restrict__ W_in,   // [DIM, PCOLS]
    const float* __restrict__ W_dt,   // [DTSZ, DIM]
    const float* __restrict__ b_dt,   // [DIM]
    float* __restrict__ bet,          // [NROWS, NST]
    float* __restrict__ gam,          // [NROWS, NST]
    float* __restrict__ dtp,          // [NROWS, DIM]
    float* __restrict__ dtxp)         // [NROWS, DIM]
{
    __shared__ float xs[ROWS][DIM];
    __shared__ float draw[ROWS][DTSZ];
    const int j = threadIdx.x;
    const int row0 = blockIdx.x * ROWS;

    #pragma unroll
    for (int r = 0; r < ROWS; ++r) xs[r][j] = x[(row0 + r) * DIM + j];
    __syncthreads();

    float acc0[ROWS] = {0.f, 0.f};
    float acc1[ROWS] = {0.f, 0.f};
    float acc2[ROWS] = {0.f, 0.f};
    const bool has2 = (j < 64);

    #pragma unroll 8
    for (int k = 0; k < DIM; ++k) {
        float w0 = W_in[k * PCOLS + j];
        float w1 = W_in[k * PCOLS + 256 + j];
        float w2 = has2 ? W_in[k * PCOLS + 512 + j] : 0.f;
        #pragma unroll
        for (int r = 0; r < ROWS; ++r) {
            float xv = xs[r][k];          // LDS broadcast
            acc0[r] = fmaf(xv, w0, acc0[r]);
            acc1[r] = fmaf(xv, w1, acc1[r]);
            acc2[r] = fmaf(xv, w2, acc2[r]);
        }
    }

    // Scatter: col c<64 -> dt_raw[c]; 64<=c<320 -> beta[c-64]; else gamma[c-320]
    #pragma unroll
    for (int r = 0; r < ROWS; ++r) {
        const int row = row0 + r;
        if (j < 64) {
            draw[r][j] = acc0[r];
            bet[row * NST + 192 + j] = acc1[r];
            gam[row * NST + 192 + j] = acc2[r];
        } else {
            bet[row * NST + (j - 64)] = acc0[r];
            gam[row * NST + (j - 64)] = acc1[r];
        }
    }
    __syncthreads();

    // dt = softplus(dt_raw @ W_dt + b_dt); dtx = dt * x
    float bd = b_dt[j];
    float accd[ROWS];
    #pragma unroll
    for (int r = 0; r < ROWS; ++r) accd[r] = bd;
    #pragma unroll 8
    for (int k = 0; k < DTSZ; ++k) {
        float w = W_dt[k * DIM + j];
        #pragma unroll
        for (int r = 0; r < ROWS; ++r) accd[r] = fmaf(draw[r][k], w, accd[r]);
    }
    #pragma unroll
    for (int r = 0; r < ROWS; ++r) {
        const int row = row0 + r;
        float v = accd[r];
        float sp = (v > 20.f) ? v : log1pf(__expf(v));
        dtp[row * DIM + j] = sp;
        dtxp[row * DIM + j] = sp * xs[r][j];
    }
}

// ---------------- Chunked scan: s <- a*s + b is affine; split L into C chunks.
constexpr int G  = 4;          // d-values per block (share beta/gamma loads, 4x ILP)
constexpr int C  = 8;          // chunks over L
constexpr int LC = LSEQ / C;   // 64 steps per chunk
constexpr int TR = 8;          // steps between output reductions in pass 3

// Pass 1: per-chunk affine summary (P = prod a, Q = folded b). No LDS.
// grid = B * (DIM/G) * C = 2*64*8 = 1024 blocks x 256 threads (thread = n).
__global__ __launch_bounds__(256) void scan_pass1(
    const float* __restrict__ alpha_log,  // [DIM, NST]
    const float* __restrict__ bet,        // [NROWS, NST]
    const float* __restrict__ dtp,        // [NROWS, DIM]
    const float* __restrict__ dtxp,       // [NROWS, DIM]
    float* __restrict__ PS,               // [B, DIM, C, NST]
    float* __restrict__ Q)                // [B, DIM, C, NST]
{
    const int n    = threadIdx.x;
    const int c    = blockIdx.x & (C - 1);
    const int dblk = (blockIdx.x >> 3) & 63;
    const int b    = blockIdx.x >> 9;
    const int d0   = dblk * G;

    float aln[G], p[G], q[G];
    #pragma unroll
    for (int g = 0; g < G; ++g) {
        aln[g] = -__expf(alpha_log[(d0 + g) * NST + n]);
        p[g] = 1.f; q[g] = 0.f;
    }

    const int rbase = b * LSEQ + c * LC;
    #pragma unroll 4
    for (int t = 0; t < LC; ++t) {
        const int r = rbase + t;
        const float be = bet[r * NST + n];                       // coalesced
        const float4 dtv4  = *(const float4*)(dtp  + r * DIM + d0);  // uniform
        const float4 dtxv4 = *(const float4*)(dtxp + r * DIM + d0);  // uniform
        const float dtv[G]  = {dtv4.x, dtv4.y, dtv4.z, dtv4.w};
        const float dtxv[G] = {dtxv4.x, dtxv4.y, dtxv4.z, dtxv4.w};
        #pragma unroll
        for (int g = 0; g < G; ++g) {
            float a = __expf(dtv[g] * aln[g]);
            q[g] = fmaf(a, q[g], dtxv[g] * be);
            p[g] *= a;
        }
    }
    #pragma unroll
    for (int g = 0; g < G; ++g) {
        const int base = ((b * DIM + d0 + g) * C + c) * NST + n;
        PS[base] = p[g];
        Q[base]  = q[g];
    }
}

// Pass 2: sequential combine across chunks; rewrites PS in-place with the
// chunk ENTRY state. grid = B*DIM = 512 blocks x 256 threads.
__global__ __launch_bounds__(256) void scan_pass2(
    float* __restrict__ PS, const float* __restrict__ Q)
{
    const int n = threadIdx.x;
    const int base = blockIdx.x * C * NST + n;
    float s = 0.f;
    #pragma unroll
    for (int c = 0; c < C; ++c) {
        const int i = base + c * NST;
        const float p  = PS[i];
        const float qq = Q[i];
        PS[i] = s;              // state entering chunk c
        s = fmaf(p, s, qq);
    }
}

// Pass 3: re-run chunk from correct entry state; produce y via deferred
// LDS transpose-reduction every TR steps. grid = 1024 blocks x 256 threads.
__global__ __launch_bounds__(256) void scan_pass3(
    const float* __restrict__ x,          // [NROWS, DIM]
    const float* __restrict__ alpha_log,  // [DIM, NST]
    const float* __restrict__ delta,      // [DIM]
    const float* __restrict__ bet,        // [NROWS, NST]
    const float* __restrict__ gam,        // [NROWS, NST]
    const float* __restrict__ dtp,        // [NROWS, DIM]
    const float* __restrict__ dtxp,       // [NROWS, DIM]
    const float* __restrict__ PS,         // [B, DIM, C, NST] entry states
    float* __restrict__ out)              // [NROWS, DIM]
{
    __shared__ float part[TR * G][NST];   // 32 x 256 x 4B = 32 KB
    const int n    = threadIdx.x;
    const int c    = blockIdx.x & (C - 1);
    const int dblk = (blockIdx.x >> 3) & 63;
    const int b    = blockIdx.x >> 9;
    const int d0   = dblk * G;

    float aln[G], s[G];
    #pragma unroll
    for (int g = 0; g < G; ++g) {
        aln[g] = -__expf(alpha_log[(d0 + g) * NST + n]);
        s[g] = PS[((b * DIM + d0 + g) * C + c) * NST + n];
    }

    const int rbase = b * LSEQ + c * LC;
    for (int t8 = 0; t8 < LC / TR; ++t8) {
        #pragma unroll
        for (int tt = 0; tt < TR; ++tt) {
            const int r = rbase + t8 * TR + tt;
            const float be = bet[r * NST + n];
            const float ga = gam[r * NST + n];
            const float4 dtv4  = *(const float4*)(dtp  + r * DIM + d0);
            const float4 dtxv4 = *(const float4*)(dtxp + r * DIM + d0);
            const float dtv[G]  = {dtv4.x, dtv4.y, dtv4.z, dtv4.w};
            const float dtxv[G] = {dtxv4.x, dtxv4.y, dtxv4.z, dtxv4.w};
            #pragma unroll
            for (int g = 0; g < G; ++g) {
                float a = __expf(dtv[g] * aln[g]);
                s[g] = fmaf(a, s[g], dtxv[g] * be);
                part[tt * G + g][n] = s[g] * ga;   // 2-way bank alias = free
            }
        }
        __syncthreads();

        // Reduce 32 rows x 256 partials with 256 threads.
        {
            const int trow = n >> 3;
            const int seg  = n & 7;
            float sum = 0.f;
            #pragma unroll
            for (int k = 0; k < 32; ++k) {
                int kk = (k + n) & 31;            // rotation: conflict-free
                sum += part[trow][seg * 32 + kk];
            }
            sum += __shfl_xor(sum, 1);
            sum += __shfl_xor(sum, 2);
            sum += __shfl_xor(sum, 4);
            if (seg == 0) {
                const int tt = trow >> 2;         // row = tt*G + g
                const int g  = trow & 3;
                const int r  = rbase + t8 * TR + tt;
                const int oidx = r * DIM + d0 + g;
                out[oidx] = sum + x[oidx] * delta[d0 + g];
            }
        }
        __syncthreads();
    }
}

extern "C" void kernel_launch(void* const* d_in, const int* in_sizes, int n_in,
                              void* d_out, int out_size, void* d_ws, size_t ws_size,
                              hipStream_t stream) {
    const float* x         = (const float*)d_in[0];
    const float* W_in      = (const float*)d_in[1];
    const float* W_dt      = (const float*)d_in[2];
    const float* b_dt      = (const float*)d_in[3];
    const float* alpha_log = (const float*)d_in[4];
    const float* delta     = (const float*)d_in[5];
    float* out = (float*)d_out;

    // Workspace: bet/gam/dtp/dtxp (4x1MB) + PS/Q (2x4MB) = 12 MB
    float* bet  = (float*)d_ws;
    float* gam  = bet  + NROWS * NST;
    float* dtp  = gam  + NROWS * NST;
    float* dtxp = dtp  + NROWS * DIM;
    float* PS   = dtxp + NROWS * DIM;
    float* Q    = PS   + BAT * DIM * C * NST;

    proj_kernel<<<NROWS / ROWS, 256, 0, stream>>>(x, W_in, W_dt, b_dt, bet, gam, dtp, dtxp);
    scan_pass1<<<BAT * (DIM / G) * C, 256, 0, stream>>>(alpha_log, bet, dtp, dtxp, PS, Q);
    scan_pass2<<<BAT * DIM, 256, 0, stream>>>(PS, Q);
    scan_pass3<<<BAT * (DIM / G) * C, 256, 0, stream>>>(x, alpha_log, delta, bet, gam, dtp, dtxp, PS, out);
}